// Round 12
// baseline (257.067 us; speedup 1.0000x reference)
//
#include <hip/hip_runtime.h>
#include <hip/hip_bf16.h>
#include <type_traits>
#include <math.h>

typedef __bf16 bf16x8 __attribute__((ext_vector_type(8)));
typedef float floatx4 __attribute__((ext_vector_type(4)));
typedef float floatx16 __attribute__((ext_vector_type(16)));

#define S_LEN 2048
#define D_DIM 128
#define NTOK (2 * 16 * 2048)  // B*H*S = 65536 rows
#define KVB 64
#define NKV (S_LEN / KVB)     // 32 kv tiles (fallback path)
#define KVB_S 32              // split path tile
#define NKV_S 32              // tiles per half (1024 kv / 32)

// ---------------------------------------------------------------------------
// proj body: stages W once, then processes 4 chunks of 64 rows.
// ---------------------------------------------------------------------------
template <typename TIN, typename TOUT>
__device__ __forceinline__ void proj_body4(
    const TIN* __restrict__ x, const float* __restrict__ W,
    const float* __restrict__ b, TOUT* __restrict__ y, float out_scale,
    int chunk0, __bf16 (*Wl)[128]) {
  const int tid = threadIdx.x;
  const int wave = tid >> 6, lane = tid & 63;
  const int g = lane >> 4, lr = lane & 15;

  for (int it = 0; it < 16; ++it) {
    int lin = it * 1024 + tid * 4;
    float4 w4 = *reinterpret_cast<const float4*>(W + lin);
    int r = lin >> 7, c = lin & 127;
    Wl[r][c]     = (__bf16)w4.x;
    Wl[r][c + 1] = (__bf16)w4.y;
    Wl[r][c + 2] = (__bf16)w4.z;
    Wl[r][c + 3] = (__bf16)w4.w;
  }
  __syncthreads();

  float be[8];
#pragma unroll
  for (int nt = 0; nt < 8; ++nt) be[nt] = b[nt * 16 + lr];

  for (int ch = 0; ch < 4; ++ch) {
    const int rbase = (chunk0 + ch) * 64;
    const int arow = rbase + wave * 16 + lr;

    floatx4 acc[8];
#pragma unroll
    for (int i = 0; i < 8; ++i) acc[i] = floatx4{0.f, 0.f, 0.f, 0.f};

#pragma unroll
    for (int kc = 0; kc < 4; ++kc) {
      bf16x8 af;
      const TIN* xp = x + (size_t)arow * D_DIM + kc * 32 + g * 8;
      if constexpr (std::is_same<TIN, float>::value) {
        float4 f0 = *reinterpret_cast<const float4*>(xp);
        float4 f1 = *reinterpret_cast<const float4*>(xp + 4);
        af[0] = (__bf16)f0.x; af[1] = (__bf16)f0.y;
        af[2] = (__bf16)f0.z; af[3] = (__bf16)f0.w;
        af[4] = (__bf16)f1.x; af[5] = (__bf16)f1.y;
        af[6] = (__bf16)f1.z; af[7] = (__bf16)f1.w;
      } else {
        af = *reinterpret_cast<const bf16x8*>(xp);
      }
#pragma unroll
      for (int nt = 0; nt < 8; ++nt) {
        bf16x8 wf = *reinterpret_cast<const bf16x8*>(&Wl[nt * 16 + lr][kc * 32 + g * 8]);
        acc[nt] = __builtin_amdgcn_mfma_f32_16x16x32_bf16(af, wf, acc[nt], 0, 0, 0);
      }
    }

#pragma unroll
    for (int nt = 0; nt < 8; ++nt) {
      int e = nt * 16 + lr;
#pragma unroll
      for (int j = 0; j < 4; ++j) {
        int row = rbase + wave * 16 + g * 4 + j;
        float val = (acc[nt][j] + be[nt]) * out_scale;
        y[(size_t)row * D_DIM + e] = (TOUT)val;
      }
    }
  }
}

__global__ __launch_bounds__(256) void qkv_proj_kernel(
    const float* __restrict__ xq, const float* __restrict__ xk,
    const float* __restrict__ xv, const float* __restrict__ Wq,
    const float* __restrict__ Wk, const float* __restrict__ Wv,
    const float* __restrict__ bq, const float* __restrict__ bk,
    const float* __restrict__ bv, __bf16* yq, __bf16* yk, __bf16* yv,
    float qscale) {
  __shared__ alignas(16) __bf16 Wl[128][128];
  const int which = blockIdx.y;
  const float* x = which == 0 ? xq : which == 1 ? xk : xv;
  const float* W = which == 0 ? Wq : which == 1 ? Wk : Wv;
  const float* b = which == 0 ? bq : which == 1 ? bk : bv;
  __bf16* y = which == 0 ? yq : which == 1 ? yk : yv;
  float sc = which == 0 ? qscale : 1.0f;
  proj_body4<float, __bf16>(x, W, b, y, sc, blockIdx.x * 4, Wl);
}

__global__ __launch_bounds__(256) void o_proj_kernel(
    const __bf16* __restrict__ x, const float* __restrict__ W,
    const float* __restrict__ b, float* __restrict__ y) {
  __shared__ alignas(16) __bf16 Wl[128][128];
  proj_body4<__bf16, float>(x, W, b, y, 1.0f, blockIdx.x * 4, Wl);
}

// o_proj with on-the-fly merge of two kv-split partials (fp32) using
// per-row weights w_i = 2^{g_i} / (2^{g0} + 2^{g1}), g_i = m_i + log2(l_i).
__global__ __launch_bounds__(256) void o_proj_merge_kernel(
    const float* __restrict__ p0, const float* __restrict__ p1,
    const float* __restrict__ g0, const float* __restrict__ g1,
    const float* __restrict__ W, const float* __restrict__ b,
    float* __restrict__ y) {
  __shared__ alignas(16) __bf16 Wl[128][128];
  const int tid = threadIdx.x;
  const int wave = tid >> 6, lane = tid & 63;
  const int g = lane >> 4, lr = lane & 15;

  for (int it = 0; it < 16; ++it) {
    int lin = it * 1024 + tid * 4;
    float4 w4 = *reinterpret_cast<const float4*>(W + lin);
    int r = lin >> 7, c = lin & 127;
    Wl[r][c]     = (__bf16)w4.x;
    Wl[r][c + 1] = (__bf16)w4.y;
    Wl[r][c + 2] = (__bf16)w4.z;
    Wl[r][c + 3] = (__bf16)w4.w;
  }
  __syncthreads();

  float be[8];
#pragma unroll
  for (int nt = 0; nt < 8; ++nt) be[nt] = b[nt * 16 + lr];

  for (int ch = 0; ch < 4; ++ch) {
    const int rbase = (blockIdx.x * 4 + ch) * 64;
    const int arow = rbase + wave * 16 + lr;

    const float ga = g0[arow], gb = g1[arow];
    const float e2 = __builtin_amdgcn_exp2f(gb - ga);
    const float w0 = 1.0f / (1.0f + e2);
    const float w1 = 1.0f - w0;

    floatx4 acc[8];
#pragma unroll
    for (int i = 0; i < 8; ++i) acc[i] = floatx4{0.f, 0.f, 0.f, 0.f};

#pragma unroll
    for (int kc = 0; kc < 4; ++kc) {
      const float* xp0 = p0 + (size_t)arow * D_DIM + kc * 32 + g * 8;
      const float* xp1 = p1 + (size_t)arow * D_DIM + kc * 32 + g * 8;
      float4 a0 = *reinterpret_cast<const float4*>(xp0);
      float4 a1 = *reinterpret_cast<const float4*>(xp0 + 4);
      float4 c0 = *reinterpret_cast<const float4*>(xp1);
      float4 c1 = *reinterpret_cast<const float4*>(xp1 + 4);
      bf16x8 af;
      af[0] = (__bf16)(w0 * a0.x + w1 * c0.x);
      af[1] = (__bf16)(w0 * a0.y + w1 * c0.y);
      af[2] = (__bf16)(w0 * a0.z + w1 * c0.z);
      af[3] = (__bf16)(w0 * a0.w + w1 * c0.w);
      af[4] = (__bf16)(w0 * a1.x + w1 * c1.x);
      af[5] = (__bf16)(w0 * a1.y + w1 * c1.y);
      af[6] = (__bf16)(w0 * a1.z + w1 * c1.z);
      af[7] = (__bf16)(w0 * a1.w + w1 * c1.w);
#pragma unroll
      for (int nt = 0; nt < 8; ++nt) {
        bf16x8 wf = *reinterpret_cast<const bf16x8*>(&Wl[nt * 16 + lr][kc * 32 + g * 8]);
        acc[nt] = __builtin_amdgcn_mfma_f32_16x16x32_bf16(af, wf, acc[nt], 0, 0, 0);
      }
    }

#pragma unroll
    for (int nt = 0; nt < 8; ++nt) {
      int e = nt * 16 + lr;
#pragma unroll
      for (int j = 0; j < 4; ++j) {
        int row = rbase + wave * 16 + g * 4 + j;
        y[(size_t)row * D_DIM + e] = acc[nt][j] + be[nt];
      }
    }
  }
}

// ---------------------------------------------------------------------------
__device__ __forceinline__ unsigned swz(int row, unsigned byteoff) {
  return byteoff ^ (((unsigned)(row ^ (row >> 3)) & 7u) << 4);
}

__device__ __forceinline__ unsigned pack2(float lo, float hi) {
  union { __bf16 h[2]; unsigned u; } r;
  r.h[0] = (__bf16)lo; r.h[1] = (__bf16)hi;
  return r.u;
}

// ---------------------------------------------------------------------------
// attn_split_kernel: kv-split flash attention. Grid (32 bh, 16 qchunk,
// 2 kv-half) = 1024 blocks -> 4 blocks/CU, 4 waves/SIMD (TLP 2x vs v11).
// KVB_S=32, double-buffered, LDS 32 KB. Chunked conflict-free layouts:
//   K [cc16][row32][16B]: byte = cc*512 + row*16 ^ ((cc&7)<<4)
//   V [c4][d128][16B]: byte = 16384 + c*2048 + d*16 + (kv&7)*2 ^ ((d>>3)&7)<<4
// Per block: online softmax over its 1024-kv half; writes normalized fp32
// partial O ([token][d]) and g = m + log2(l) per row.
// ---------------------------------------------------------------------------
__global__ __launch_bounds__(256, 4) void attn_split_kernel(
    const __bf16* __restrict__ q, const __bf16* __restrict__ k,
    const __bf16* __restrict__ v, float* __restrict__ part0,
    float* __restrict__ part1, float* __restrict__ g0w,
    float* __restrict__ g1w) {
  __shared__ alignas(16) unsigned char smem[32768];

  const int tid = threadIdx.x;
  const int wave = tid >> 6, lane = tid & 63;
  const int ql = lane & 31;
  const int h = lane >> 5;

  const int bh = blockIdx.x;
  const int qbase = blockIdx.y * 128;
  const int half = blockIdx.z;
  float* part = half ? part1 : part0;
  float* gw = half ? g1w : g0w;

  const __bf16* qp = q + (size_t)bh * S_LEN * D_DIM;
  const __bf16* kp = k + (size_t)bh * S_LEN * D_DIM + (size_t)half * 1024 * D_DIM;
  const __bf16* vp = v + (size_t)bh * S_LEN * D_DIM + (size_t)half * 1024 * D_DIM;

  const int qrow = qbase + wave * 32 + ql;
  bf16x8 qf[8];
#pragma unroll
  for (int kc = 0; kc < 8; ++kc)
    qf[kc] = *reinterpret_cast<const bf16x8*>(
        qp + (size_t)qrow * D_DIM + kc * 16 + h * 8);

  floatx16 ot[4];
#pragma unroll
  for (int d = 0; d < 4; ++d)
#pragma unroll
    for (int r = 0; r < 16; ++r) ot[d][r] = 0.f;
  float m_r = -1e30f, l_r = 0.f;

  // staging map: 256 thr cover 32 rows x 128 cols; cc = col-chunk, pr2 row-pair
  const int cc = tid & 15;
  const int pr2 = (tid >> 4) * 2;
  const int ce = cc * 8;

  // lane-resident LDS address bases
  unsigned Rk[4];
#pragma unroll
  for (int x = 0; x < 4; ++x)
    Rk[x] = (unsigned)(h * 512) +
            (((unsigned)(ql * 16)) ^ ((unsigned)h << 4) ^ ((unsigned)x << 5));
  const unsigned Rv0 = 16384u + (unsigned)(h * 2048) +
                       (((unsigned)(ql * 16)) ^ (((unsigned)(ql >> 3)) << 4));
  const unsigned Rv1 = Rv0 ^ 64u;
  const unsigned kx = ((unsigned)(cc & 7)) << 4;
  const unsigned Wk0 = ((unsigned)(cc * 512 + pr2 * 16)) ^ kx;
  const unsigned Wk1 = ((unsigned)(cc * 512 + (pr2 + 1) * 16)) ^ kx;
  unsigned Wv_[8];
  {
    unsigned C = 16384u + (unsigned)((pr2 >> 3) * 2048 + 128 * cc + (pr2 & 7) * 2);
#pragma unroll
    for (int e = 0; e < 8; ++e)
      Wv_[e] = C + (((unsigned)(e * 16)) ^ kx);
  }

  // prologue: stage tile 0 into buf 0
  {
    const __bf16* kr = kp + (size_t)pr2 * D_DIM + ce;
    const __bf16* vr = vp + (size_t)pr2 * D_DIM + ce;
    bf16x8 kA0 = *reinterpret_cast<const bf16x8*>(kr);
    bf16x8 kA1 = *reinterpret_cast<const bf16x8*>(kr + D_DIM);
    union { bf16x8 v8; unsigned short s[8]; } vA0, vA1;
    vA0.v8 = *reinterpret_cast<const bf16x8*>(vr);
    vA1.v8 = *reinterpret_cast<const bf16x8*>(vr + D_DIM);
    *reinterpret_cast<bf16x8*>(smem + Wk0) = kA0;
    *reinterpret_cast<bf16x8*>(smem + Wk1) = kA1;
#pragma unroll
    for (int e = 0; e < 8; ++e) {
      unsigned w = (unsigned)vA0.s[e] | ((unsigned)vA1.s[e] << 16);
      *reinterpret_cast<unsigned*>(smem + Wv_[e]) = w;
    }
  }

  const __bf16* krp = kp + ((size_t)KVB_S + pr2) * D_DIM + ce;
  const __bf16* vrp = vp + ((size_t)KVB_S + pr2) * D_DIM + ce;

#pragma unroll 2
  for (int t = 0; t < NKV_S; ++t) {
    const unsigned cb = (unsigned)(t & 1) * 8192u;
    const bool hn = (t + 1 < NKV_S);

    __syncthreads();  // buf[cur] staged; previous tile's readers done

    bf16x8 kA0, kA1;
    union { bf16x8 v8; unsigned short s[8]; } vA0, vA1;
    if (hn) {
      kA0 = *reinterpret_cast<const bf16x8*>(krp);
      kA1 = *reinterpret_cast<const bf16x8*>(krp + D_DIM);
      vA0.v8 = *reinterpret_cast<const bf16x8*>(vrp);
      vA1.v8 = *reinterpret_cast<const bf16x8*>(vrp + D_DIM);
      krp += (size_t)KVB_S * D_DIM;
      vrp += (size_t)KVB_S * D_DIM;
    }

    // ---- QK^T: S^T[32 kv][32 q] ----
    floatx16 st;
#pragma unroll
    for (int r = 0; r < 16; ++r) st[r] = 0.f;
    __builtin_amdgcn_s_setprio(1);
#pragma unroll
    for (int kc = 0; kc < 8; ++kc) {
      bf16x8 kf = *reinterpret_cast<const bf16x8*>(
          smem + cb + Rk[kc & 3] + (unsigned)(kc * 1024));
      st = __builtin_amdgcn_mfma_f32_32x32x16_bf16(kf, qf[kc], st, 0, 0, 0);
    }
    __builtin_amdgcn_s_setprio(0);

    // ---- softmax (exp2 domain), T13 defer-rescale ----
    float t8[8];
#pragma unroll
    for (int i = 0; i < 8; ++i) t8[i] = fmaxf(st[i], st[i + 8]);
    float pmax = fmaxf(fmaxf(fmaxf(t8[0], t8[4]), fmaxf(t8[1], t8[5])),
                       fmaxf(fmaxf(t8[2], t8[6]), fmaxf(t8[3], t8[7])));
    pmax = fmaxf(pmax, __shfl_xor(pmax, 32));
    if (!__all(pmax - m_r <= 8.0f)) {
      float mnew = fmaxf(m_r, pmax);
      float sc_f = __builtin_amdgcn_exp2f(m_r - mnew);
      m_r = mnew;
      l_r *= sc_f;
#pragma unroll
      for (int d = 0; d < 4; ++d)
#pragma unroll
        for (int r = 0; r < 16; ++r) ot[d][r] *= sc_f;
    }
#pragma unroll
    for (int r = 0; r < 16; ++r)
      st[r] = __builtin_amdgcn_exp2f(st[r] - m_r);
    float s8[8];
#pragma unroll
    for (int i = 0; i < 8; ++i) s8[i] = st[i] + st[i + 8];
    float psum = ((s8[0] + s8[4]) + (s8[1] + s8[5])) +
                 ((s8[2] + s8[6]) + (s8[3] + s8[7]));
    psum += __shfl_xor(psum, 32);
    l_r += psum;

    // ---- P^T B-fragments + PV ----
#pragma unroll
    for (int ks = 0; ks < 2; ++ks) {
      const int r2a = 2 * ks;
      const int r2b = r2a + 1;
      unsigned ua0 = pack2(st[r2a * 4 + 0], st[r2a * 4 + 1]);
      unsigned ua1 = pack2(st[r2a * 4 + 2], st[r2a * 4 + 3]);
      unsigned ub0 = pack2(st[r2b * 4 + 0], st[r2b * 4 + 1]);
      unsigned ub1 = pack2(st[r2b * 4 + 2], st[r2b * 4 + 3]);
      union { unsigned u[4]; bf16x8 v8; } pw;
#if __has_builtin(__builtin_amdgcn_permlane32_swap)
      {
        auto r0 = __builtin_amdgcn_permlane32_swap(ua0, ub0, false, false);
        auto r1 = __builtin_amdgcn_permlane32_swap(ua1, ub1, false, false);
        pw.u[0] = r0[0];
        pw.u[1] = r1[0];
        pw.u[2] = r0[1];
        pw.u[3] = r1[1];
      }
#else
      {
        unsigned a0x = __shfl_xor(ua0, 32), a1x = __shfl_xor(ua1, 32);
        unsigned b0x = __shfl_xor(ub0, 32), b1x = __shfl_xor(ub1, 32);
        pw.u[0] = h ? b0x : ua0;
        pw.u[1] = h ? b1x : ua1;
        pw.u[2] = h ? ub0 : a0x;
        pw.u[3] = h ? ub1 : a1x;
      }
#endif
      __builtin_amdgcn_s_setprio(1);
#pragma unroll
      for (int db = 0; db < 4; ++db) {
        const unsigned base = (db & 1) ? Rv1 : Rv0;
        bf16x8 vf = *reinterpret_cast<const bf16x8*>(
            smem + cb + base + (unsigned)(ks * 4096 + db * 512));
        ot[db] = __builtin_amdgcn_mfma_f32_32x32x16_bf16(vf, pw.v8, ot[db], 0, 0, 0);
      }
      __builtin_amdgcn_s_setprio(0);
    }

    // ---- write staged tile t+1 into buf[nxt] ----
    if (hn) {
      const unsigned nb = cb ^ 8192u;
      *reinterpret_cast<bf16x8*>(smem + nb + Wk0) = kA0;
      *reinterpret_cast<bf16x8*>(smem + nb + Wk1) = kA1;
#pragma unroll
      for (int e = 0; e < 8; ++e) {
        unsigned w = (unsigned)vA0.s[e] | ((unsigned)vA1.s[e] << 16);
        *reinterpret_cast<unsigned*>(smem + nb + Wv_[e]) = w;
      }
    }
  }

  // ---- epilogue: normalized fp32 partial + g; 2-pass LDS transpose ----
  const float inv_l = 1.0f / l_r;
  if (h == 0) gw[(size_t)bh * S_LEN + qbase + wave * 32 + ql] =
      m_r + __log2f(l_r);
  float* pout = part + ((size_t)bh * S_LEN + qbase) * D_DIM;

#pragma unroll
  for (int p = 0; p < 2; ++p) {
    __syncthreads();
    if ((wave >> 1) == p) {
      int qloc = (wave & 1) * 32 + ql;
#pragma unroll
      for (int db = 0; db < 4; ++db)
#pragma unroll
        for (int r = 0; r < 16; ++r) {
          int d = db * 32 + (r & 3) + 8 * (r >> 2) + 4 * h;
          *reinterpret_cast<float*>(
              smem + (((unsigned)(qloc * 512 + d * 4)) ^
                      (((unsigned)(qloc & 7)) << 4))) = ot[db][r] * inv_l;
        }
    }
    __syncthreads();
#pragma unroll
    for (int it = 0; it < 8; ++it) {
      int qr = tid >> 2;
      int ds = (tid & 3) * 32 + it * 4;
      float4 val = *reinterpret_cast<const float4*>(
          smem + (((unsigned)(qr * 512 + ds * 4)) ^ (((unsigned)(qr & 7)) << 4)));
      *reinterpret_cast<float4*>(pout + (size_t)(p * 64 + qr) * D_DIM + ds) = val;
    }
  }
}

// ---------------------------------------------------------------------------
// attn_kernel (fallback, = round-11 kernel verbatim)
// ---------------------------------------------------------------------------
__global__ __launch_bounds__(256, 2) void attn_kernel(
    const __bf16* __restrict__ q, const __bf16* __restrict__ k,
    const __bf16* __restrict__ v, __bf16* __restrict__ o) {
  __shared__ alignas(16) unsigned char smem[65536];

  const int tid = threadIdx.x;
  const int wave = tid >> 6, lane = tid & 63;
  const int ql = lane & 31;
  const int h = lane >> 5;

  const int bh = blockIdx.x;
  const int qbase = blockIdx.y * 128;
  const __bf16* qp = q + (size_t)bh * S_LEN * D_DIM;
  const __bf16* kp = k + (size_t)bh * S_LEN * D_DIM;
  const __bf16* vp = v + (size_t)bh * S_LEN * D_DIM;
  __bf16* op = o + (size_t)bh * S_LEN * D_DIM;

  const int qrow = qbase + wave * 32 + ql;
  bf16x8 qf[8];
#pragma unroll
  for (int kc = 0; kc < 8; ++kc)
    qf[kc] = *reinterpret_cast<const bf16x8*>(
        qp + (size_t)qrow * D_DIM + kc * 16 + h * 8);

  floatx16 ot[4];
#pragma unroll
  for (int d = 0; d < 4; ++d)
#pragma unroll
    for (int r = 0; r < 16; ++r) ot[d][r] = 0.f;
  float m_r = -1e30f, l_r = 0.f;

  const int cc = tid & 15;
  const int pr = (tid >> 4) * 2;
  const int ce = cc * 8;

  unsigned Rk[4];
#pragma unroll
  for (int x = 0; x < 4; ++x)
    Rk[x] = (unsigned)(h * 1024) +
            (((unsigned)(ql * 16)) ^ ((unsigned)h << 4) ^ ((unsigned)x << 5));
  const unsigned Rv0 = 32768u + (unsigned)(h * 2048) +
                       (((unsigned)(ql * 16)) ^ (((unsigned)(ql >> 3)) << 4));
  const unsigned Rv1 = Rv0 ^ 64u;
  const unsigned kx = ((unsigned)(cc & 7)) << 4;
  const unsigned Wk0 = ((unsigned)(cc * 1024 + pr * 16)) ^ kx;
  const unsigned Wk1 = ((unsigned)(cc * 1024 + (pr + 1) * 16)) ^ kx;
  unsigned Wv_[8];
  {
    unsigned vbase = 32768u + (unsigned)((pr >> 3) * 2048 + ce * 16 + (pr & 7) * 2);
#pragma unroll
    for (int e = 0; e < 8; ++e)
      Wv_[e] = vbase | (((unsigned)e << 4) ^ kx);
  }

  {
    const __bf16* kr = kp + (size_t)pr * D_DIM + ce;
    const __bf16* vr = vp + (size_t)pr * D_DIM + ce;
    bf16x8 kA0 = *reinterpret_cast<const bf16x8*>(kr);
    bf16x8 kA1 = *reinterpret_cast<const bf16x8*>(kr + D_DIM);
    bf16x8 kB0 = *reinterpret_cast<const bf16x8*>(kr + 32 * D_DIM);
    bf16x8 kB1 = *reinterpret_cast<const bf16x8*>(kr + 33 * D_DIM);
    union { bf16x8 v8; unsigned short s[8]; } vA0, vA1, vB0, vB1;
    vA0.v8 = *reinterpret_cast<const bf16x8*>(vr);
    vA1.v8 = *reinterpret_cast<const bf16x8*>(vr + D_DIM);
    vB0.v8 = *reinterpret_cast<const bf16x8*>(vr + 32 * D_DIM);
    vB1.v8 = *reinterpret_cast<const bf16x8*>(vr + 33 * D_DIM);
    *reinterpret_cast<bf16x8*>(smem + Wk0) = kA0;
    *reinterpret_cast<bf16x8*>(smem + Wk1) = kA1;
    *reinterpret_cast<bf16x8*>(smem + Wk0 + 512u) = kB0;
    *reinterpret_cast<bf16x8*>(smem + Wk1 + 512u) = kB1;
#pragma unroll
    for (int e = 0; e < 8; ++e) {
      unsigned w0 = (unsigned)vA0.s[e] | ((unsigned)vA1.s[e] << 16);
      unsigned w1 = (unsigned)vB0.s[e] | ((unsigned)vB1.s[e] << 16);
      *reinterpret_cast<unsigned*>(smem + Wv_[e]) = w0;
      *reinterpret_cast<unsigned*>(smem + Wv_[e] + 8192u) = w1;
    }
  }

  const __bf16* krp = kp + ((size_t)KVB + pr) * D_DIM + ce;
  const __bf16* vrp = vp + ((size_t)KVB + pr) * D_DIM + ce;

#pragma unroll 2
  for (int t = 0; t < NKV; ++t) {
    const unsigned cb = (unsigned)(t & 1) * 16384u;
    const bool hn = (t + 1 < NKV);

    __syncthreads();

    bf16x8 kA0, kA1, kB0, kB1;
    union { bf16x8 v8; unsigned short s[8]; } vA0, vA1, vB0, vB1;
    if (hn) {
      kA0 = *reinterpret_cast<const bf16x8*>(krp);
      kA1 = *reinterpret_cast<const bf16x8*>(krp + D_DIM);
      kB0 = *reinterpret_cast<const bf16x8*>(krp + 32 * D_DIM);
      kB1 = *reinterpret_cast<const bf16x8*>(krp + 33 * D_DIM);
      vA0.v8 = *reinterpret_cast<const bf16x8*>(vrp);
      vA1.v8 = *reinterpret_cast<const bf16x8*>(vrp + D_DIM);
      vB0.v8 = *reinterpret_cast<const bf16x8*>(vrp + 32 * D_DIM);
      vB1.v8 = *reinterpret_cast<const bf16x8*>(vrp + 33 * D_DIM);
      krp += (size_t)KVB * D_DIM;
      vrp += (size_t)KVB * D_DIM;
    }

    floatx16 st[2];
#pragma unroll
    for (int kvh = 0; kvh < 2; ++kvh)
#pragma unroll
      for (int r = 0; r < 16; ++r) st[kvh][r] = 0.f;
    __builtin_amdgcn_s_setprio(1);
#pragma unroll
    for (int kc = 0; kc < 8; ++kc) {
      bf16x8 kf0 = *reinterpret_cast<const bf16x8*>(
          smem + cb + Rk[kc & 3] + (unsigned)(kc * 2048));
      bf16x8 kf1 = *reinterpret_cast<const bf16x8*>(
          smem + cb + Rk[kc & 3] + (unsigned)(kc * 2048 + 512));
      st[0] = __builtin_amdgcn_mfma_f32_32x32x16_bf16(kf0, qf[kc], st[0], 0, 0, 0);
      st[1] = __builtin_amdgcn_mfma_f32_32x32x16_bf16(kf1, qf[kc], st[1], 0, 0, 0);
    }
    __builtin_amdgcn_s_setprio(0);

    float t8[8];
#pragma unroll
    for (int i = 0; i < 8; ++i)
      t8[i] = fmaxf(fmaxf(st[0][i], st[0][i + 8]), fmaxf(st[1][i], st[1][i + 8]));
    float pmax = fmaxf(fmaxf(fmaxf(t8[0], t8[4]), fmaxf(t8[1], t8[5])),
                       fmaxf(fmaxf(t8[2], t8[6]), fmaxf(t8[3], t8[7])));
    pmax = fmaxf(pmax, __shfl_xor(pmax, 32));
    if (!__all(pmax - m_r <= 8.0f)) {
      float mnew = fmaxf(m_r, pmax);
      float sc_f = __builtin_amdgcn_exp2f(m_r - mnew);
      m_r = mnew;
      l_r *= sc_f;
#pragma unroll
      for (int d = 0; d < 4; ++d)
#pragma unroll
        for (int r = 0; r < 16; ++r) ot[d][r] *= sc_f;
    }
#pragma unroll
    for (int kvh = 0; kvh < 2; ++kvh)
#pragma unroll
      for (int r = 0; r < 16; ++r)
        st[kvh][r] = __builtin_amdgcn_exp2f(st[kvh][r] - m_r);
    float s8[8];
#pragma unroll
    for (int i = 0; i < 8; ++i)
      s8[i] = (st[0][i] + st[0][i + 8]) + (st[1][i] + st[1][i + 8]);
    float psum = ((s8[0] + s8[4]) + (s8[1] + s8[5])) +
                 ((s8[2] + s8[6]) + (s8[3] + s8[7]));
    psum += __shfl_xor(psum, 32);
    l_r += psum;

#pragma unroll
    for (int ks = 0; ks < 4; ++ks) {
      const int kvh = ks >> 1;
      const int r2a = (2 * ks) & 3;
      const int r2b = r2a + 1;
      unsigned ua0 = pack2(st[kvh][r2a * 4 + 0], st[kvh][r2a * 4 + 1]);
      unsigned ua1 = pack2(st[kvh][r2a * 4 + 2], st[kvh][r2a * 4 + 3]);
      unsigned ub0 = pack2(st[kvh][r2b * 4 + 0], st[kvh][r2b * 4 + 1]);
      unsigned ub1 = pack2(st[kvh][r2b * 4 + 2], st[kvh][r2b * 4 + 3]);
      union { unsigned u[4]; bf16x8 v8; } pw;
#if __has_builtin(__builtin_amdgcn_permlane32_swap)
      {
        auto r0 = __builtin_amdgcn_permlane32_swap(ua0, ub0, false, false);
        auto r1 = __builtin_amdgcn_permlane32_swap(ua1, ub1, false, false);
        pw.u[0] = r0[0];
        pw.u[1] = r1[0];
        pw.u[2] = r0[1];
        pw.u[3] = r1[1];
      }
#else
      {
        unsigned a0x = __shfl_xor(ua0, 32), a1x = __shfl_xor(ua1, 32);
        unsigned b0x = __shfl_xor(ub0, 32), b1x = __shfl_xor(ub1, 32);
        pw.u[0] = h ? b0x : ua0;
        pw.u[1] = h ? b1x : ua1;
        pw.u[2] = h ? ub0 : a0x;
        pw.u[3] = h ? ub1 : a1x;
      }
#endif
      __builtin_amdgcn_s_setprio(1);
#pragma unroll
      for (int db = 0; db < 4; ++db) {
        const unsigned base = (db & 1) ? Rv1 : Rv0;
        bf16x8 vf = *reinterpret_cast<const bf16x8*>(
            smem + cb + base + (unsigned)(ks * 4096 + db * 512));
        ot[db] = __builtin_amdgcn_mfma_f32_32x32x16_bf16(vf, pw.v8, ot[db], 0, 0, 0);
      }
      __builtin_amdgcn_s_setprio(0);
    }

    if (hn) {
      const unsigned nb = cb ^ 16384u;
      *reinterpret_cast<bf16x8*>(smem + nb + Wk0) = kA0;
      *reinterpret_cast<bf16x8*>(smem + nb + Wk1) = kA1;
      *reinterpret_cast<bf16x8*>(smem + nb + Wk0 + 512u) = kB0;
      *reinterpret_cast<bf16x8*>(smem + nb + Wk1 + 512u) = kB1;
#pragma unroll
      for (int e = 0; e < 8; ++e) {
        unsigned w0 = (unsigned)vA0.s[e] | ((unsigned)vA1.s[e] << 16);
        unsigned w1 = (unsigned)vB0.s[e] | ((unsigned)vB1.s[e] << 16);
        *reinterpret_cast<unsigned*>(smem + nb + Wv_[e]) = w0;
        *reinterpret_cast<unsigned*>(smem + nb + Wv_[e] + 8192u) = w1;
      }
    }
  }

  __syncthreads();
  const float inv_l = 1.0f / l_r;
  const int qloc = wave * 32 + ql;
#pragma unroll
  for (int db = 0; db < 4; ++db)
#pragma unroll
    for (int r = 0; r < 16; ++r) {
      int d = db * 32 + (r & 3) + 8 * (r >> 2) + 4 * h;
      *reinterpret_cast<__bf16*>(smem + swz(qloc, qloc * 256u + d * 2u)) =
          (__bf16)(ot[db][r] * inv_l);
    }
  __syncthreads();
#pragma unroll
  for (int it = 0; it < 8; ++it) {
    int r = tid >> 1;
    int c = (tid & 1) * 64 + it * 8;
    bf16x8 val = *reinterpret_cast<const bf16x8*>(smem + swz(r, r * 256u + c * 2u));
    *reinterpret_cast<bf16x8*>(op + (size_t)(qbase + r) * D_DIM + c) = val;
  }
}

// ---------------------------------------------------------------------------
extern "C" void kernel_launch(void* const* d_in, const int* in_sizes, int n_in,
                              void* d_out, int out_size, void* d_ws, size_t ws_size,
                              hipStream_t stream) {
  const float* query = (const float*)d_in[0];
  const float* key_  = (const float*)d_in[1];
  const float* value = (const float*)d_in[2];
  const float* Wq = (const float*)d_in[3];
  const float* bq = (const float*)d_in[4];
  const float* Wk = (const float*)d_in[5];
  const float* bk = (const float*)d_in[6];
  const float* Wv = (const float*)d_in[7];
  const float* bv = (const float*)d_in[8];
  const float* Wo = (const float*)d_in[9];
  const float* bo = (const float*)d_in[10];

  const size_t vbytes = (size_t)NTOK * D_DIM * 2;   // bf16 V
  const size_t pbytes = (size_t)NTOK * D_DIM * 4;   // fp32 partial O
  const size_t gbytes = (size_t)NTOK * 4;           // fp32 stats
  const size_t need_split = vbytes + 2 * pbytes + 2 * gbytes;  // ~84.4 MB

  __bf16* vws = (__bf16*)d_ws;
  __bf16* qws = (__bf16*)d_out;
  __bf16* kws = qws + (size_t)NTOK * D_DIM;

  const float qscale = 0.1275174490036f;  // log2(e)/sqrt(128)

  qkv_proj_kernel<<<dim3(NTOK / 256, 3), dim3(256), 0, stream>>>(
      query, key_, value, Wq, Wk, Wv, bq, bk, bv, qws, kws, vws, qscale);

  if (ws_size >= need_split) {
    // kv-split path: 4 blocks/CU attn + merge fused into o_proj
    float* p0 = (float*)((char*)d_ws + vbytes);
    float* p1 = (float*)((char*)d_ws + vbytes + pbytes);
    float* g0 = (float*)((char*)d_ws + vbytes + 2 * pbytes);
    float* g1 = (float*)((char*)d_ws + vbytes + 2 * pbytes + gbytes);

    attn_split_kernel<<<dim3(32, 16, 2), dim3(256), 0, stream>>>(
        qws, kws, vws, p0, p1, g0, g1);

    o_proj_merge_kernel<<<NTOK / 256, dim3(256), 0, stream>>>(
        p0, p1, g0, g1, Wo, bo, (float*)d_out);
  } else {
    // fallback: round-11 proven path
    __bf16* aws = vws + (size_t)NTOK * D_DIM;
    attn_kernel<<<dim3(32, 16), dim3(256), 0, stream>>>(qws, kws, vws, aws);
    o_proj_kernel<<<NTOK / 256, dim3(256), 0, stream>>>(aws, Wo, bo, (float*)d_out);
  }
}

// Round 13
// 132.042 us; speedup vs baseline: 1.9469x; 1.9469x over previous
//
#include <hip/hip_runtime.h>
#include <hip/hip_bf16.h>
#include <type_traits>
#include <math.h>

typedef __bf16 bf16x8 __attribute__((ext_vector_type(8)));
typedef float floatx4 __attribute__((ext_vector_type(4)));
typedef float floatx16 __attribute__((ext_vector_type(16)));

#define S_LEN 2048
#define D_DIM 128
#define NTOK (2 * 16 * 2048)  // B*H*S = 65536 rows
#define KVB 64
#define NKV (S_LEN / KVB)     // 32 kv tiles

// ---------------------------------------------------------------------------
// proj body: stages W once, then processes 4 chunks of 64 rows.
// ---------------------------------------------------------------------------
template <typename TIN, typename TOUT>
__device__ __forceinline__ void proj_body4(
    const TIN* __restrict__ x, const float* __restrict__ W,
    const float* __restrict__ b, TOUT* __restrict__ y, float out_scale,
    int chunk0, __bf16 (*Wl)[128]) {
  const int tid = threadIdx.x;
  const int wave = tid >> 6, lane = tid & 63;
  const int g = lane >> 4, lr = lane & 15;

  for (int it = 0; it < 16; ++it) {
    int lin = it * 1024 + tid * 4;
    float4 w4 = *reinterpret_cast<const float4*>(W + lin);
    int r = lin >> 7, c = lin & 127;
    Wl[r][c]     = (__bf16)w4.x;
    Wl[r][c + 1] = (__bf16)w4.y;
    Wl[r][c + 2] = (__bf16)w4.z;
    Wl[r][c + 3] = (__bf16)w4.w;
  }
  __syncthreads();

  float be[8];
#pragma unroll
  for (int nt = 0; nt < 8; ++nt) be[nt] = b[nt * 16 + lr];

  for (int ch = 0; ch < 4; ++ch) {
    const int rbase = (chunk0 + ch) * 64;
    const int arow = rbase + wave * 16 + lr;

    floatx4 acc[8];
#pragma unroll
    for (int i = 0; i < 8; ++i) acc[i] = floatx4{0.f, 0.f, 0.f, 0.f};

#pragma unroll
    for (int kc = 0; kc < 4; ++kc) {
      bf16x8 af;
      const TIN* xp = x + (size_t)arow * D_DIM + kc * 32 + g * 8;
      if constexpr (std::is_same<TIN, float>::value) {
        float4 f0 = *reinterpret_cast<const float4*>(xp);
        float4 f1 = *reinterpret_cast<const float4*>(xp + 4);
        af[0] = (__bf16)f0.x; af[1] = (__bf16)f0.y;
        af[2] = (__bf16)f0.z; af[3] = (__bf16)f0.w;
        af[4] = (__bf16)f1.x; af[5] = (__bf16)f1.y;
        af[6] = (__bf16)f1.z; af[7] = (__bf16)f1.w;
      } else {
        af = *reinterpret_cast<const bf16x8*>(xp);
      }
#pragma unroll
      for (int nt = 0; nt < 8; ++nt) {
        bf16x8 wf = *reinterpret_cast<const bf16x8*>(&Wl[nt * 16 + lr][kc * 32 + g * 8]);
        acc[nt] = __builtin_amdgcn_mfma_f32_16x16x32_bf16(af, wf, acc[nt], 0, 0, 0);
      }
    }

#pragma unroll
    for (int nt = 0; nt < 8; ++nt) {
      int e = nt * 16 + lr;
#pragma unroll
      for (int j = 0; j < 4; ++j) {
        int row = rbase + wave * 16 + g * 4 + j;
        float val = (acc[nt][j] + be[nt]) * out_scale;
        y[(size_t)row * D_DIM + e] = (TOUT)val;
      }
    }
  }
}

__global__ __launch_bounds__(256) void qkv_proj_kernel(
    const float* __restrict__ xq, const float* __restrict__ xk,
    const float* __restrict__ xv, const float* __restrict__ Wq,
    const float* __restrict__ Wk, const float* __restrict__ Wv,
    const float* __restrict__ bq, const float* __restrict__ bk,
    const float* __restrict__ bv, __bf16* yq, __bf16* yk, __bf16* yv,
    float qscale) {
  __shared__ alignas(16) __bf16 Wl[128][128];
  const int which = blockIdx.y;
  const float* x = which == 0 ? xq : which == 1 ? xk : xv;
  const float* W = which == 0 ? Wq : which == 1 ? Wk : Wv;
  const float* b = which == 0 ? bq : which == 1 ? bk : bv;
  __bf16* y = which == 0 ? yq : which == 1 ? yk : yv;
  float sc = which == 0 ? qscale : 1.0f;
  proj_body4<float, __bf16>(x, W, b, y, sc, blockIdx.x * 4, Wl);
}

__global__ __launch_bounds__(256) void o_proj_kernel(
    const __bf16* __restrict__ x, const float* __restrict__ W,
    const float* __restrict__ b, float* __restrict__ y) {
  __shared__ alignas(16) __bf16 Wl[128][128];
  proj_body4<__bf16, float>(x, W, b, y, 1.0f, blockIdx.x * 4, Wl);
}

// ---------------------------------------------------------------------------
// epilogue-only swizzle (one-time O transpose staging)
__device__ __forceinline__ unsigned swz(int row, unsigned byteoff) {
  return byteoff ^ (((unsigned)(row ^ (row >> 3)) & 7u) << 4);
}

__device__ __forceinline__ unsigned pack2(float lo, float hi) {
  union { __bf16 h[2]; unsigned u; } r;
  r.h[0] = (__bf16)lo; r.h[1] = (__bf16)hi;
  return r.u;
}

// ---------------------------------------------------------------------------
// attn_kernel v13 = r11 structure + (a) staging ds_writes moved from loop
// tail to right after QK (overlap with softmax VALU + PV), (b) V staging as
// 8 x b64 per thread (4 consecutive kv rows/thread) instead of 16 x b32.
//
// LDS layouts (identical read side to r11):
//   K [cc 16][row 64][16B]: byte = (cc*1024 + row*16) ^ ((cc&7)<<4)
//   V [c 8][d 128][16B]:    byte = 32768 + c*2048 + d*16 + (kv&7)*2,
//                           XOR ((d>>3)&7)<<4
// Staging map: rg = tid>>4 (16 groups), cc = tid&15; thread owns kv rows
// pr4 = rg*4 .. +3, d-cols ce = cc*8 .. +7. K: 4 b128 writes (consecutive
// slots). V: per e in 0..7 one b64 = 4 rows' bf16 at d=ce+e; bank =
// 4*(e^(cc&7)) + 2*(rg&1) -> exactly 4 accesses/bank (volume minimum).
//
// Write-early legality: top barrier of body t guarantees ALL waves finished
// body t-1 entirely, incl. QK(t-1) reads of bufK[nxt] and PV(t-1) reads of
// bufV[nxt]. Hence writes to buf[nxt] are safe ANYWHERE in body t; only the
// in-body position changed (tail -> after QK). Readers of the new data wait
// at barrier(t+1). vmcnt for the staged loads (issued after barrier) lands
// after QK (~>= L2 latency; FETCH shows loads are L2-hits).
// ---------------------------------------------------------------------------
__global__ __launch_bounds__(256, 2) void attn_kernel(
    const __bf16* __restrict__ q, const __bf16* __restrict__ k,
    const __bf16* __restrict__ v, __bf16* __restrict__ o) {
  __shared__ alignas(16) unsigned char smem[65536];

  const int tid = threadIdx.x;
  const int wave = tid >> 6, lane = tid & 63;
  const int ql = lane & 31;
  const int h = lane >> 5;

  const int bh = blockIdx.x;
  const int qbase = blockIdx.y * 128;
  const __bf16* qp = q + (size_t)bh * S_LEN * D_DIM;
  const __bf16* kp = k + (size_t)bh * S_LEN * D_DIM;
  const __bf16* vp = v + (size_t)bh * S_LEN * D_DIM;
  __bf16* op = o + (size_t)bh * S_LEN * D_DIM;

  const int qrow = qbase + wave * 32 + ql;
  bf16x8 qf[8];
#pragma unroll
  for (int kc = 0; kc < 8; ++kc)
    qf[kc] = *reinterpret_cast<const bf16x8*>(
        qp + (size_t)qrow * D_DIM + kc * 16 + h * 8);

  floatx16 ot[4];
#pragma unroll
  for (int d = 0; d < 4; ++d)
#pragma unroll
    for (int r = 0; r < 16; ++r) ot[d][r] = 0.f;
  float m_r = -1e30f, l_r = 0.f;

  // staging map: 4 consecutive kv rows per thread
  const int cc = tid & 15;
  const int pr4 = (tid >> 4) * 4;
  const int ce = cc * 8;

  // ---- lane-resident LDS address bases (loop-invariant) ----
  unsigned Rk[4];
#pragma unroll
  for (int x = 0; x < 4; ++x)
    Rk[x] = (unsigned)(h * 1024) +
            (((unsigned)(ql * 16)) ^ ((unsigned)h << 4) ^ ((unsigned)x << 5));
  const unsigned Rv0 = 32768u + (unsigned)(h * 2048) +
                       (((unsigned)(ql * 16)) ^ (((unsigned)(ql >> 3)) << 4));
  const unsigned Rv1 = Rv0 ^ 64u;
  const unsigned kx = ((unsigned)(cc & 7)) << 4;
  unsigned Wk_[4];
#pragma unroll
  for (int j = 0; j < 4; ++j)
    Wk_[j] = ((unsigned)(cc * 1024 + (pr4 + j) * 16)) ^ kx;
  unsigned Wv_[8];
  {
    unsigned vbase = 32768u + (unsigned)((pr4 >> 3) * 2048 + ce * 16 + (pr4 & 7) * 2);
#pragma unroll
    for (int e = 0; e < 8; ++e)
      Wv_[e] = vbase | (((unsigned)e << 4) ^ kx);
  }

  // ---- prologue: stage tile 0 into buf 0 ----
  {
    const __bf16* kr = kp + (size_t)pr4 * D_DIM + ce;
    const __bf16* vr = vp + (size_t)pr4 * D_DIM + ce;
    bf16x8 kR[4];
    union { bf16x8 v8; unsigned short s[8]; } vR[4];
#pragma unroll
    for (int j = 0; j < 4; ++j) {
      kR[j] = *reinterpret_cast<const bf16x8*>(kr + j * D_DIM);
      vR[j].v8 = *reinterpret_cast<const bf16x8*>(vr + j * D_DIM);
    }
#pragma unroll
    for (int j = 0; j < 4; ++j)
      *reinterpret_cast<bf16x8*>(smem + Wk_[j]) = kR[j];
#pragma unroll
    for (int e = 0; e < 8; ++e) {
      uint2 w;
      w.x = (unsigned)vR[0].s[e] | ((unsigned)vR[1].s[e] << 16);
      w.y = (unsigned)vR[2].s[e] | ((unsigned)vR[3].s[e] << 16);
      *reinterpret_cast<uint2*>(smem + Wv_[e]) = w;
    }
  }

  // running prefetch pointers (tile t+1)
  const __bf16* krp = kp + ((size_t)KVB + pr4) * D_DIM + ce;
  const __bf16* vrp = vp + ((size_t)KVB + pr4) * D_DIM + ce;

#pragma unroll 2
  for (int t = 0; t < NKV; ++t) {
    const unsigned cb = (unsigned)(t & 1) * 16384u;  // const after unroll-2
    const bool hn = (t + 1 < NKV);

    __syncthreads();  // buf[cur] staged; ALL waves done with body t-1
                      // (so buf[nxt] regions have no remaining readers).

    bf16x8 kR[4];
    union { bf16x8 v8; unsigned short s[8]; } vR[4];
    if (hn) {  // issue next-tile global loads (after barrier: no drain)
#pragma unroll
      for (int j = 0; j < 4; ++j) {
        kR[j] = *reinterpret_cast<const bf16x8*>(krp + j * D_DIM);
        vR[j].v8 = *reinterpret_cast<const bf16x8*>(vrp + j * D_DIM);
      }
      krp += (size_t)KVB * D_DIM;
      vrp += (size_t)KVB * D_DIM;
    }

    // ---- QK^T: S^T[kv][q] ----
    floatx16 st[2];
#pragma unroll
    for (int kvh = 0; kvh < 2; ++kvh)
#pragma unroll
      for (int r = 0; r < 16; ++r) st[kvh][r] = 0.f;
    __builtin_amdgcn_s_setprio(1);
#pragma unroll
    for (int kc = 0; kc < 8; ++kc) {
      bf16x8 kf0 = *reinterpret_cast<const bf16x8*>(
          smem + cb + Rk[kc & 3] + (unsigned)(kc * 2048));
      bf16x8 kf1 = *reinterpret_cast<const bf16x8*>(
          smem + cb + Rk[kc & 3] + (unsigned)(kc * 2048 + 512));
      st[0] = __builtin_amdgcn_mfma_f32_32x32x16_bf16(kf0, qf[kc], st[0], 0, 0, 0);
      st[1] = __builtin_amdgcn_mfma_f32_32x32x16_bf16(kf1, qf[kc], st[1], 0, 0, 0);
    }
    __builtin_amdgcn_s_setprio(0);

    // ---- write staged tile t+1 into buf[nxt] EARLY (drains under
    //      softmax VALU + PV; legality per header comment) ----
    if (hn) {
      const unsigned nb = cb ^ 16384u;
#pragma unroll
      for (int j = 0; j < 4; ++j)
        *reinterpret_cast<bf16x8*>(smem + nb + Wk_[j]) = kR[j];
#pragma unroll
      for (int e = 0; e < 8; ++e) {
        uint2 w;
        w.x = (unsigned)vR[0].s[e] | ((unsigned)vR[1].s[e] << 16);
        w.y = (unsigned)vR[2].s[e] | ((unsigned)vR[3].s[e] << 16);
        *reinterpret_cast<uint2*>(smem + nb + Wv_[e]) = w;
      }
    }

    // ---- softmax (exp2 domain), tree max/sum, T13 defer-rescale ----
    float t8[8];
#pragma unroll
    for (int i = 0; i < 8; ++i)
      t8[i] = fmaxf(fmaxf(st[0][i], st[0][i + 8]), fmaxf(st[1][i], st[1][i + 8]));
    float pmax = fmaxf(fmaxf(fmaxf(t8[0], t8[4]), fmaxf(t8[1], t8[5])),
                       fmaxf(fmaxf(t8[2], t8[6]), fmaxf(t8[3], t8[7])));
    pmax = fmaxf(pmax, __shfl_xor(pmax, 32));
    if (!__all(pmax - m_r <= 8.0f)) {
      float mnew = fmaxf(m_r, pmax);
      float sc_f = __builtin_amdgcn_exp2f(m_r - mnew);
      m_r = mnew;
      l_r *= sc_f;
#pragma unroll
      for (int d = 0; d < 4; ++d)
#pragma unroll
        for (int r = 0; r < 16; ++r) ot[d][r] *= sc_f;
    }
#pragma unroll
    for (int kvh = 0; kvh < 2; ++kvh)
#pragma unroll
      for (int r = 0; r < 16; ++r)
        st[kvh][r] = __builtin_amdgcn_exp2f(st[kvh][r] - m_r);
    float s8[8];
#pragma unroll
    for (int i = 0; i < 8; ++i)
      s8[i] = (st[0][i] + st[0][i + 8]) + (st[1][i] + st[1][i + 8]);
    float psum = ((s8[0] + s8[4]) + (s8[1] + s8[5])) +
                 ((s8[2] + s8[6]) + (s8[3] + s8[7]));
    psum += __shfl_xor(psum, 32);
    l_r += psum;

    // ---- P^T B-fragments + PV ----
#pragma unroll
    for (int ks = 0; ks < 4; ++ks) {
      const int kvh = ks >> 1;
      const int r2a = (2 * ks) & 3;
      const int r2b = r2a + 1;
      unsigned ua0 = pack2(st[kvh][r2a * 4 + 0], st[kvh][r2a * 4 + 1]);
      unsigned ua1 = pack2(st[kvh][r2a * 4 + 2], st[kvh][r2a * 4 + 3]);
      unsigned ub0 = pack2(st[kvh][r2b * 4 + 0], st[kvh][r2b * 4 + 1]);
      unsigned ub1 = pack2(st[kvh][r2b * 4 + 2], st[kvh][r2b * 4 + 3]);
      union { unsigned u[4]; bf16x8 v8; } pw;
#if __has_builtin(__builtin_amdgcn_permlane32_swap)
      {
        auto r0 = __builtin_amdgcn_permlane32_swap(ua0, ub0, false, false);
        auto r1 = __builtin_amdgcn_permlane32_swap(ua1, ub1, false, false);
        pw.u[0] = r0[0];
        pw.u[1] = r1[0];
        pw.u[2] = r0[1];
        pw.u[3] = r1[1];
      }
#else
      {
        unsigned a0x = __shfl_xor(ua0, 32), a1x = __shfl_xor(ua1, 32);
        unsigned b0x = __shfl_xor(ub0, 32), b1x = __shfl_xor(ub1, 32);
        pw.u[0] = h ? b0x : ua0;
        pw.u[1] = h ? b1x : ua1;
        pw.u[2] = h ? ub0 : a0x;
        pw.u[3] = h ? ub1 : a1x;
      }
#endif
      __builtin_amdgcn_s_setprio(1);
#pragma unroll
      for (int db = 0; db < 4; ++db) {
        const unsigned base = (db & 1) ? Rv1 : Rv0;
        bf16x8 vf = *reinterpret_cast<const bf16x8*>(
            smem + cb + base + (unsigned)(ks * 4096 + db * 512));
        ot[db] = __builtin_amdgcn_mfma_f32_32x32x16_bf16(vf, pw.v8, ot[db], 0, 0, 0);
      }
      __builtin_amdgcn_s_setprio(0);
    }
  }

  // ---- epilogue: O^T -> LDS transpose -> coalesced stores ----
  __syncthreads();
  const float inv_l = 1.0f / l_r;
  const int qloc = wave * 32 + ql;
#pragma unroll
  for (int db = 0; db < 4; ++db)
#pragma unroll
    for (int r = 0; r < 16; ++r) {
      int d = db * 32 + (r & 3) + 8 * (r >> 2) + 4 * h;
      *reinterpret_cast<__bf16*>(smem + swz(qloc, qloc * 256u + d * 2u)) =
          (__bf16)(ot[db][r] * inv_l);
    }
  __syncthreads();
#pragma unroll
  for (int it = 0; it < 8; ++it) {
    int r = tid >> 1;
    int c = (tid & 1) * 64 + it * 8;
    bf16x8 val = *reinterpret_cast<const bf16x8*>(smem + swz(r, r * 256u + c * 2u));
    *reinterpret_cast<bf16x8*>(op + (size_t)(qbase + r) * D_DIM + c) = val;
  }
}

// ---------------------------------------------------------------------------
extern "C" void kernel_launch(void* const* d_in, const int* in_sizes, int n_in,
                              void* d_out, int out_size, void* d_ws, size_t ws_size,
                              hipStream_t stream) {
  const float* query = (const float*)d_in[0];
  const float* key_  = (const float*)d_in[1];
  const float* value = (const float*)d_in[2];
  const float* Wq = (const float*)d_in[3];
  const float* bq = (const float*)d_in[4];
  const float* Wk = (const float*)d_in[5];
  const float* bk = (const float*)d_in[6];
  const float* Wv = (const float*)d_in[7];
  const float* bv = (const float*)d_in[8];
  const float* Wo = (const float*)d_in[9];
  const float* bo = (const float*)d_in[10];

  // scratch: v + attn-out in d_ws; q + k scratch inside d_out (bf16, fully
  // overwritten by the final fp32 projection)
  __bf16* vws = (__bf16*)d_ws;
  __bf16* aws = vws + (size_t)NTOK * D_DIM;
  __bf16* qws = (__bf16*)d_out;
  __bf16* kws = qws + (size_t)NTOK * D_DIM;

  // q scale = log2(e)/sqrt(128): softmax runs in exp2 domain
  const float qscale = 0.1275174490036f;

  qkv_proj_kernel<<<dim3(NTOK / 256, 3), dim3(256), 0, stream>>>(
      query, key_, value, Wq, Wk, Wv, bq, bk, bv, qws, kws, vws, qscale);

  attn_kernel<<<dim3(32, 16), dim3(256), 0, stream>>>(qws, kws, vws, aws);

  o_proj_kernel<<<NTOK / 256, dim3(256), 0, stream>>>(aws, Wo, bo, (float*)d_out);
}

// Round 14
// 123.543 us; speedup vs baseline: 2.0808x; 1.0688x over previous
//
#include <hip/hip_runtime.h>
#include <hip/hip_bf16.h>
#include <type_traits>
#include <math.h>

typedef __bf16 bf16x8 __attribute__((ext_vector_type(8)));
typedef float floatx4 __attribute__((ext_vector_type(4)));
typedef float floatx16 __attribute__((ext_vector_type(16)));

#define S_LEN 2048
#define D_DIM 128
#define NTOK (2 * 16 * 2048)  // B*H*S = 65536 rows
#define KVB 64
#define NKV (S_LEN / KVB)     // 32 kv tiles

// ---------------------------------------------------------------------------
// proj body: stages W once, then processes 4 chunks of 64 rows.
// ---------------------------------------------------------------------------
template <typename TIN, typename TOUT>
__device__ __forceinline__ void proj_body4(
    const TIN* __restrict__ x, const float* __restrict__ W,
    const float* __restrict__ b, TOUT* __restrict__ y, float out_scale,
    int chunk0, __bf16 (*Wl)[128]) {
  const int tid = threadIdx.x;
  const int wave = tid >> 6, lane = tid & 63;
  const int g = lane >> 4, lr = lane & 15;

  for (int it = 0; it < 16; ++it) {
    int lin = it * 1024 + tid * 4;
    float4 w4 = *reinterpret_cast<const float4*>(W + lin);
    int r = lin >> 7, c = lin & 127;
    Wl[r][c]     = (__bf16)w4.x;
    Wl[r][c + 1] = (__bf16)w4.y;
    Wl[r][c + 2] = (__bf16)w4.z;
    Wl[r][c + 3] = (__bf16)w4.w;
  }
  __syncthreads();

  float be[8];
#pragma unroll
  for (int nt = 0; nt < 8; ++nt) be[nt] = b[nt * 16 + lr];

  for (int ch = 0; ch < 4; ++ch) {
    const int rbase = (chunk0 + ch) * 64;
    const int arow = rbase + wave * 16 + lr;

    floatx4 acc[8];
#pragma unroll
    for (int i = 0; i < 8; ++i) acc[i] = floatx4{0.f, 0.f, 0.f, 0.f};

#pragma unroll
    for (int kc = 0; kc < 4; ++kc) {
      bf16x8 af;
      const TIN* xp = x + (size_t)arow * D_DIM + kc * 32 + g * 8;
      if constexpr (std::is_same<TIN, float>::value) {
        float4 f0 = *reinterpret_cast<const float4*>(xp);
        float4 f1 = *reinterpret_cast<const float4*>(xp + 4);
        af[0] = (__bf16)f0.x; af[1] = (__bf16)f0.y;
        af[2] = (__bf16)f0.z; af[3] = (__bf16)f0.w;
        af[4] = (__bf16)f1.x; af[5] = (__bf16)f1.y;
        af[6] = (__bf16)f1.z; af[7] = (__bf16)f1.w;
      } else {
        af = *reinterpret_cast<const bf16x8*>(xp);
      }
#pragma unroll
      for (int nt = 0; nt < 8; ++nt) {
        bf16x8 wf = *reinterpret_cast<const bf16x8*>(&Wl[nt * 16 + lr][kc * 32 + g * 8]);
        acc[nt] = __builtin_amdgcn_mfma_f32_16x16x32_bf16(af, wf, acc[nt], 0, 0, 0);
      }
    }

#pragma unroll
    for (int nt = 0; nt < 8; ++nt) {
      int e = nt * 16 + lr;
#pragma unroll
      for (int j = 0; j < 4; ++j) {
        int row = rbase + wave * 16 + g * 4 + j;
        float val = (acc[nt][j] + be[nt]) * out_scale;
        y[(size_t)row * D_DIM + e] = (TOUT)val;
      }
    }
  }
}

__global__ __launch_bounds__(256) void qkv_proj_kernel(
    const float* __restrict__ xq, const float* __restrict__ xk,
    const float* __restrict__ xv, const float* __restrict__ Wq,
    const float* __restrict__ Wk, const float* __restrict__ Wv,
    const float* __restrict__ bq, const float* __restrict__ bk,
    const float* __restrict__ bv, __bf16* yq, __bf16* yk, __bf16* yv,
    float qscale) {
  __shared__ alignas(16) __bf16 Wl[128][128];
  const int which = blockIdx.y;
  const float* x = which == 0 ? xq : which == 1 ? xk : xv;
  const float* W = which == 0 ? Wq : which == 1 ? Wk : Wv;
  const float* b = which == 0 ? bq : which == 1 ? bk : bv;
  __bf16* y = which == 0 ? yq : which == 1 ? yk : yv;
  float sc = which == 0 ? qscale : 1.0f;
  proj_body4<float, __bf16>(x, W, b, y, sc, blockIdx.x * 4, Wl);
}

__global__ __launch_bounds__(256) void o_proj_kernel(
    const __bf16* __restrict__ x, const float* __restrict__ W,
    const float* __restrict__ b, float* __restrict__ y) {
  __shared__ alignas(16) __bf16 Wl[128][128];
  proj_body4<__bf16, float>(x, W, b, y, 1.0f, blockIdx.x * 4, Wl);
}

// ---------------------------------------------------------------------------
// epilogue swizzle (O tile + Wo tile staging)
__device__ __forceinline__ unsigned swz(int row, unsigned byteoff) {
  return byteoff ^ (((unsigned)(row ^ (row >> 3)) & 7u) << 4);
}

__device__ __forceinline__ unsigned pack2(float lo, float hi) {
  union { __bf16 h[2]; unsigned u; } r;
  r.h[0] = (__bf16)lo; r.h[1] = (__bf16)hi;
  return r.u;
}

// ---------------------------------------------------------------------------
// attn_fused_kernel = r13 attn k-loop + fused O-projection epilogue.
//
// K-loop (identical to r13): chunked conflict-free LDS layouts, single
// barrier/tile, prefetch-after-barrier, write-early staging, swapped
// 32x32x16 QK^T, in-register exp2-domain softmax, T13 defer-rescale,
// in-register P^T via permlane32_swap.
//
// Fused epilogue: (1) barrier; (2) O^T -> LDS[0..32K) as row-major bf16
// (swizzled, divided by l); Wo fp32 -> LDS[32K..64K) as bf16 (swizzled);
// (3) barrier; (4) per wave, proj_body-style 64x MFMA 16x16x32 computing
// out[q][e] = O[q][:] . Wo[e][:] + bo[e]; write fp32 d_out directly.
// Eliminates the separate o_proj kernel (launch + 16.8 MB re-read).
// REQUIRES q/k NOT aliased into d_out (d_out is written while other blocks
// still read q/k) -> q,k,v all live in d_ws (50.3 MB; ws_size >= 84.4 MB
// proven in round 12). Fallback to split path otherwise.
// ---------------------------------------------------------------------------
__global__ __launch_bounds__(256, 2) void attn_fused_kernel(
    const __bf16* __restrict__ q, const __bf16* __restrict__ k,
    const __bf16* __restrict__ v, const float* __restrict__ Wo,
    const float* __restrict__ bo, float* __restrict__ out) {
  __shared__ alignas(16) unsigned char smem[65536];

  const int tid = threadIdx.x;
  const int wave = tid >> 6, lane = tid & 63;
  const int ql = lane & 31;
  const int h = lane >> 5;

  const int bh = blockIdx.x;
  const int qbase = blockIdx.y * 128;
  const __bf16* qp = q + (size_t)bh * S_LEN * D_DIM;
  const __bf16* kp = k + (size_t)bh * S_LEN * D_DIM;
  const __bf16* vp = v + (size_t)bh * S_LEN * D_DIM;

  const int qrow = qbase + wave * 32 + ql;
  bf16x8 qf[8];
#pragma unroll
  for (int kc = 0; kc < 8; ++kc)
    qf[kc] = *reinterpret_cast<const bf16x8*>(
        qp + (size_t)qrow * D_DIM + kc * 16 + h * 8);

  floatx16 ot[4];
#pragma unroll
  for (int d = 0; d < 4; ++d)
#pragma unroll
    for (int r = 0; r < 16; ++r) ot[d][r] = 0.f;
  float m_r = -1e30f, l_r = 0.f;

  // staging map: 4 consecutive kv rows per thread
  const int cc = tid & 15;
  const int pr4 = (tid >> 4) * 4;
  const int ce = cc * 8;

  // ---- lane-resident LDS address bases (loop-invariant) ----
  unsigned Rk[4];
#pragma unroll
  for (int x = 0; x < 4; ++x)
    Rk[x] = (unsigned)(h * 1024) +
            (((unsigned)(ql * 16)) ^ ((unsigned)h << 4) ^ ((unsigned)x << 5));
  const unsigned Rv0 = 32768u + (unsigned)(h * 2048) +
                       (((unsigned)(ql * 16)) ^ (((unsigned)(ql >> 3)) << 4));
  const unsigned Rv1 = Rv0 ^ 64u;
  const unsigned kx = ((unsigned)(cc & 7)) << 4;
  unsigned Wk_[4];
#pragma unroll
  for (int j = 0; j < 4; ++j)
    Wk_[j] = ((unsigned)(cc * 1024 + (pr4 + j) * 16)) ^ kx;
  unsigned Wv_[8];
  {
    unsigned vbase = 32768u + (unsigned)((pr4 >> 3) * 2048 + ce * 16 + (pr4 & 7) * 2);
#pragma unroll
    for (int e = 0; e < 8; ++e)
      Wv_[e] = vbase | (((unsigned)e << 4) ^ kx);
  }

  // ---- prologue: stage tile 0 into buf 0 ----
  {
    const __bf16* kr = kp + (size_t)pr4 * D_DIM + ce;
    const __bf16* vr = vp + (size_t)pr4 * D_DIM + ce;
    bf16x8 kR[4];
    union { bf16x8 v8; unsigned short s[8]; } vR[4];
#pragma unroll
    for (int j = 0; j < 4; ++j) {
      kR[j] = *reinterpret_cast<const bf16x8*>(kr + j * D_DIM);
      vR[j].v8 = *reinterpret_cast<const bf16x8*>(vr + j * D_DIM);
    }
#pragma unroll
    for (int j = 0; j < 4; ++j)
      *reinterpret_cast<bf16x8*>(smem + Wk_[j]) = kR[j];
#pragma unroll
    for (int e = 0; e < 8; ++e) {
      uint2 w;
      w.x = (unsigned)vR[0].s[e] | ((unsigned)vR[1].s[e] << 16);
      w.y = (unsigned)vR[2].s[e] | ((unsigned)vR[3].s[e] << 16);
      *reinterpret_cast<uint2*>(smem + Wv_[e]) = w;
    }
  }

  const __bf16* krp = kp + ((size_t)KVB + pr4) * D_DIM + ce;
  const __bf16* vrp = vp + ((size_t)KVB + pr4) * D_DIM + ce;

#pragma unroll 2
  for (int t = 0; t < NKV; ++t) {
    const unsigned cb = (unsigned)(t & 1) * 16384u;
    const bool hn = (t + 1 < NKV);

    __syncthreads();  // buf[cur] staged; all waves done with body t-1

    bf16x8 kR[4];
    union { bf16x8 v8; unsigned short s[8]; } vR[4];
    if (hn) {
#pragma unroll
      for (int j = 0; j < 4; ++j) {
        kR[j] = *reinterpret_cast<const bf16x8*>(krp + j * D_DIM);
        vR[j].v8 = *reinterpret_cast<const bf16x8*>(vrp + j * D_DIM);
      }
      krp += (size_t)KVB * D_DIM;
      vrp += (size_t)KVB * D_DIM;
    }

    // ---- QK^T ----
    floatx16 st[2];
#pragma unroll
    for (int kvh = 0; kvh < 2; ++kvh)
#pragma unroll
      for (int r = 0; r < 16; ++r) st[kvh][r] = 0.f;
    __builtin_amdgcn_s_setprio(1);
#pragma unroll
    for (int kc = 0; kc < 8; ++kc) {
      bf16x8 kf0 = *reinterpret_cast<const bf16x8*>(
          smem + cb + Rk[kc & 3] + (unsigned)(kc * 2048));
      bf16x8 kf1 = *reinterpret_cast<const bf16x8*>(
          smem + cb + Rk[kc & 3] + (unsigned)(kc * 2048 + 512));
      st[0] = __builtin_amdgcn_mfma_f32_32x32x16_bf16(kf0, qf[kc], st[0], 0, 0, 0);
      st[1] = __builtin_amdgcn_mfma_f32_32x32x16_bf16(kf1, qf[kc], st[1], 0, 0, 0);
    }
    __builtin_amdgcn_s_setprio(0);

    // ---- staging writes (drain under softmax + PV) ----
    if (hn) {
      const unsigned nb = cb ^ 16384u;
#pragma unroll
      for (int j = 0; j < 4; ++j)
        *reinterpret_cast<bf16x8*>(smem + nb + Wk_[j]) = kR[j];
#pragma unroll
      for (int e = 0; e < 8; ++e) {
        uint2 w;
        w.x = (unsigned)vR[0].s[e] | ((unsigned)vR[1].s[e] << 16);
        w.y = (unsigned)vR[2].s[e] | ((unsigned)vR[3].s[e] << 16);
        *reinterpret_cast<uint2*>(smem + nb + Wv_[e]) = w;
      }
    }

    // ---- softmax (exp2 domain), T13 defer-rescale ----
    float t8[8];
#pragma unroll
    for (int i = 0; i < 8; ++i)
      t8[i] = fmaxf(fmaxf(st[0][i], st[0][i + 8]), fmaxf(st[1][i], st[1][i + 8]));
    float pmax = fmaxf(fmaxf(fmaxf(t8[0], t8[4]), fmaxf(t8[1], t8[5])),
                       fmaxf(fmaxf(t8[2], t8[6]), fmaxf(t8[3], t8[7])));
    pmax = fmaxf(pmax, __shfl_xor(pmax, 32));
    if (!__all(pmax - m_r <= 8.0f)) {
      float mnew = fmaxf(m_r, pmax);
      float sc_f = __builtin_amdgcn_exp2f(m_r - mnew);
      m_r = mnew;
      l_r *= sc_f;
#pragma unroll
      for (int d = 0; d < 4; ++d)
#pragma unroll
        for (int r = 0; r < 16; ++r) ot[d][r] *= sc_f;
    }
#pragma unroll
    for (int kvh = 0; kvh < 2; ++kvh)
#pragma unroll
      for (int r = 0; r < 16; ++r)
        st[kvh][r] = __builtin_amdgcn_exp2f(st[kvh][r] - m_r);
    float s8[8];
#pragma unroll
    for (int i = 0; i < 8; ++i)
      s8[i] = (st[0][i] + st[0][i + 8]) + (st[1][i] + st[1][i + 8]);
    float psum = ((s8[0] + s8[4]) + (s8[1] + s8[5])) +
                 ((s8[2] + s8[6]) + (s8[3] + s8[7]));
    psum += __shfl_xor(psum, 32);
    l_r += psum;

    // ---- P^T B-fragments + PV ----
#pragma unroll
    for (int ks = 0; ks < 4; ++ks) {
      const int kvh = ks >> 1;
      const int r2a = (2 * ks) & 3;
      const int r2b = r2a + 1;
      unsigned ua0 = pack2(st[kvh][r2a * 4 + 0], st[kvh][r2a * 4 + 1]);
      unsigned ua1 = pack2(st[kvh][r2a * 4 + 2], st[kvh][r2a * 4 + 3]);
      unsigned ub0 = pack2(st[kvh][r2b * 4 + 0], st[kvh][r2b * 4 + 1]);
      unsigned ub1 = pack2(st[kvh][r2b * 4 + 2], st[kvh][r2b * 4 + 3]);
      union { unsigned u[4]; bf16x8 v8; } pw;
#if __has_builtin(__builtin_amdgcn_permlane32_swap)
      {
        auto r0 = __builtin_amdgcn_permlane32_swap(ua0, ub0, false, false);
        auto r1 = __builtin_amdgcn_permlane32_swap(ua1, ub1, false, false);
        pw.u[0] = r0[0];
        pw.u[1] = r1[0];
        pw.u[2] = r0[1];
        pw.u[3] = r1[1];
      }
#else
      {
        unsigned a0x = __shfl_xor(ua0, 32), a1x = __shfl_xor(ua1, 32);
        unsigned b0x = __shfl_xor(ub0, 32), b1x = __shfl_xor(ub1, 32);
        pw.u[0] = h ? b0x : ua0;
        pw.u[1] = h ? b1x : ua1;
        pw.u[2] = h ? ub0 : a0x;
        pw.u[3] = h ? ub1 : a1x;
      }
#endif
      __builtin_amdgcn_s_setprio(1);
#pragma unroll
      for (int db = 0; db < 4; ++db) {
        const unsigned base = (db & 1) ? Rv1 : Rv0;
        bf16x8 vf = *reinterpret_cast<const bf16x8*>(
            smem + cb + base + (unsigned)(ks * 4096 + db * 512));
        ot[db] = __builtin_amdgcn_mfma_f32_32x32x16_bf16(vf, pw.v8, ot[db], 0, 0, 0);
      }
      __builtin_amdgcn_s_setprio(0);
    }
  }

  // ==== fused epilogue: O -> LDS; Wo -> LDS; proj; write fp32 d_out ====
  __syncthreads();  // all waves done with K/V LDS

  // (a) O^T -> LDS[0..32K) as row-major bf16 (divided by l), swizzled
  {
    const float inv_l = 1.0f / l_r;
    const int qloc = wave * 32 + ql;
#pragma unroll
    for (int db = 0; db < 4; ++db)
#pragma unroll
      for (int r = 0; r < 16; ++r) {
        int d = db * 32 + (r & 3) + 8 * (r >> 2) + 4 * h;
        *reinterpret_cast<__bf16*>(smem + swz(qloc, qloc * 256u + d * 2u)) =
            (__bf16)(ot[db][r] * inv_l);
      }
  }
  // (b) Wo fp32 -> LDS[32K..64K) as bf16, swizzled rows
  for (int it = 0; it < 16; ++it) {
    int lin = it * 1024 + tid * 4;
    float4 w4 = *reinterpret_cast<const float4*>(Wo + lin);
    int r = lin >> 7, c = lin & 127;
    unsigned off = 32768u + swz(r, (unsigned)(r * 256 + c * 2));
    __bf16 b4[4] = {(__bf16)w4.x, (__bf16)w4.y, (__bf16)w4.z, (__bf16)w4.w};
    *reinterpret_cast<uint2*>(smem + off) = *reinterpret_cast<uint2*>(b4);
  }
  __syncthreads();

  // (c) proj: out[q][e] = O[q][:] . Wo[e][:] + bo[e]
  const int g4 = lane >> 4;      // 0..3 (k-slice group)
  const int lr = lane & 15;      // A row / C col
  float be[8];
#pragma unroll
  for (int nt = 0; nt < 8; ++nt) be[nt] = bo[nt * 16 + lr];

#pragma unroll
  for (int rt = 0; rt < 2; ++rt) {
    const int arow = wave * 32 + rt * 16 + lr;  // local O row
    floatx4 acc[8];
#pragma unroll
    for (int i = 0; i < 8; ++i) acc[i] = floatx4{0.f, 0.f, 0.f, 0.f};
#pragma unroll
    for (int kc = 0; kc < 4; ++kc) {
      bf16x8 af = *reinterpret_cast<const bf16x8*>(
          smem + swz(arow, (unsigned)(arow * 256 + (kc * 32 + g4 * 8) * 2)));
#pragma unroll
      for (int nt = 0; nt < 8; ++nt) {
        int wrow = nt * 16 + lr;
        bf16x8 wf = *reinterpret_cast<const bf16x8*>(
            smem + 32768u + swz(wrow, (unsigned)(wrow * 256 + (kc * 32 + g4 * 8) * 2)));
        acc[nt] = __builtin_amdgcn_mfma_f32_16x16x32_bf16(af, wf, acc[nt], 0, 0, 0);
      }
    }
#pragma unroll
    for (int nt = 0; nt < 8; ++nt) {
      int e = nt * 16 + lr;
#pragma unroll
      for (int j = 0; j < 4; ++j) {
        int row = qbase + wave * 32 + rt * 16 + g4 * 4 + j;
        out[((size_t)bh * S_LEN + row) * D_DIM + e] = acc[nt][j] + be[nt];
      }
    }
  }
}

// ---------------------------------------------------------------------------
// attn_kernel (fallback path: writes bf16 O to aws; = r13 behavior)
// ---------------------------------------------------------------------------
__global__ __launch_bounds__(256, 2) void attn_kernel(
    const __bf16* __restrict__ q, const __bf16* __restrict__ k,
    const __bf16* __restrict__ v, __bf16* __restrict__ o) {
  __shared__ alignas(16) unsigned char smem[65536];

  const int tid = threadIdx.x;
  const int wave = tid >> 6, lane = tid & 63;
  const int ql = lane & 31;
  const int h = lane >> 5;

  const int bh = blockIdx.x;
  const int qbase = blockIdx.y * 128;
  const __bf16* qp = q + (size_t)bh * S_LEN * D_DIM;
  const __bf16* kp = k + (size_t)bh * S_LEN * D_DIM;
  const __bf16* vp = v + (size_t)bh * S_LEN * D_DIM;
  __bf16* op = o + (size_t)bh * S_LEN * D_DIM;

  const int qrow = qbase + wave * 32 + ql;
  bf16x8 qf[8];
#pragma unroll
  for (int kc = 0; kc < 8; ++kc)
    qf[kc] = *reinterpret_cast<const bf16x8*>(
        qp + (size_t)qrow * D_DIM + kc * 16 + h * 8);

  floatx16 ot[4];
#pragma unroll
  for (int d = 0; d < 4; ++d)
#pragma unroll
    for (int r = 0; r < 16; ++r) ot[d][r] = 0.f;
  float m_r = -1e30f, l_r = 0.f;

  const int cc = tid & 15;
  const int pr4 = (tid >> 4) * 4;
  const int ce = cc * 8;

  unsigned Rk[4];
#pragma unroll
  for (int x = 0; x < 4; ++x)
    Rk[x] = (unsigned)(h * 1024) +
            (((unsigned)(ql * 16)) ^ ((unsigned)h << 4) ^ ((unsigned)x << 5));
  const unsigned Rv0 = 32768u + (unsigned)(h * 2048) +
                       (((unsigned)(ql * 16)) ^ (((unsigned)(ql >> 3)) << 4));
  const unsigned Rv1 = Rv0 ^ 64u;
  const unsigned kx = ((unsigned)(cc & 7)) << 4;
  unsigned Wk_[4];
#pragma unroll
  for (int j = 0; j < 4; ++j)
    Wk_[j] = ((unsigned)(cc * 1024 + (pr4 + j) * 16)) ^ kx;
  unsigned Wv_[8];
  {
    unsigned vbase = 32768u + (unsigned)((pr4 >> 3) * 2048 + ce * 16 + (pr4 & 7) * 2);
#pragma unroll
    for (int e = 0; e < 8; ++e)
      Wv_[e] = vbase | (((unsigned)e << 4) ^ kx);
  }

  {
    const __bf16* kr = kp + (size_t)pr4 * D_DIM + ce;
    const __bf16* vr = vp + (size_t)pr4 * D_DIM + ce;
    bf16x8 kR[4];
    union { bf16x8 v8; unsigned short s[8]; } vR[4];
#pragma unroll
    for (int j = 0; j < 4; ++j) {
      kR[j] = *reinterpret_cast<const bf16x8*>(kr + j * D_DIM);
      vR[j].v8 = *reinterpret_cast<const bf16x8*>(vr + j * D_DIM);
    }
#pragma unroll
    for (int j = 0; j < 4; ++j)
      *reinterpret_cast<bf16x8*>(smem + Wk_[j]) = kR[j];
#pragma unroll
    for (int e = 0; e < 8; ++e) {
      uint2 w;
      w.x = (unsigned)vR[0].s[e] | ((unsigned)vR[1].s[e] << 16);
      w.y = (unsigned)vR[2].s[e] | ((unsigned)vR[3].s[e] << 16);
      *reinterpret_cast<uint2*>(smem + Wv_[e]) = w;
    }
  }

  const __bf16* krp = kp + ((size_t)KVB + pr4) * D_DIM + ce;
  const __bf16* vrp = vp + ((size_t)KVB + pr4) * D_DIM + ce;

#pragma unroll 2
  for (int t = 0; t < NKV; ++t) {
    const unsigned cb = (unsigned)(t & 1) * 16384u;
    const bool hn = (t + 1 < NKV);

    __syncthreads();

    bf16x8 kR[4];
    union { bf16x8 v8; unsigned short s[8]; } vR[4];
    if (hn) {
#pragma unroll
      for (int j = 0; j < 4; ++j) {
        kR[j] = *reinterpret_cast<const bf16x8*>(krp + j * D_DIM);
        vR[j].v8 = *reinterpret_cast<const bf16x8*>(vrp + j * D_DIM);
      }
      krp += (size_t)KVB * D_DIM;
      vrp += (size_t)KVB * D_DIM;
    }

    floatx16 st[2];
#pragma unroll
    for (int kvh = 0; kvh < 2; ++kvh)
#pragma unroll
      for (int r = 0; r < 16; ++r) st[kvh][r] = 0.f;
    __builtin_amdgcn_s_setprio(1);
#pragma unroll
    for (int kc = 0; kc < 8; ++kc) {
      bf16x8 kf0 = *reinterpret_cast<const bf16x8*>(
          smem + cb + Rk[kc & 3] + (unsigned)(kc * 2048));
      bf16x8 kf1 = *reinterpret_cast<const bf16x8*>(
          smem + cb + Rk[kc & 3] + (unsigned)(kc * 2048 + 512));
      st[0] = __builtin_amdgcn_mfma_f32_32x32x16_bf16(kf0, qf[kc], st[0], 0, 0, 0);
      st[1] = __builtin_amdgcn_mfma_f32_32x32x16_bf16(kf1, qf[kc], st[1], 0, 0, 0);
    }
    __builtin_amdgcn_s_setprio(0);

    if (hn) {
      const unsigned nb = cb ^ 16384u;
#pragma unroll
      for (int j = 0; j < 4; ++j)
        *reinterpret_cast<bf16x8*>(smem + nb + Wk_[j]) = kR[j];
#pragma unroll
      for (int e = 0; e < 8; ++e) {
        uint2 w;
        w.x = (unsigned)vR[0].s[e] | ((unsigned)vR[1].s[e] << 16);
        w.y = (unsigned)vR[2].s[e] | ((unsigned)vR[3].s[e] << 16);
        *reinterpret_cast<uint2*>(smem + nb + Wv_[e]) = w;
      }
    }

    float t8[8];
#pragma unroll
    for (int i = 0; i < 8; ++i)
      t8[i] = fmaxf(fmaxf(st[0][i], st[0][i + 8]), fmaxf(st[1][i], st[1][i + 8]));
    float pmax = fmaxf(fmaxf(fmaxf(t8[0], t8[4]), fmaxf(t8[1], t8[5])),
                       fmaxf(fmaxf(t8[2], t8[6]), fmaxf(t8[3], t8[7])));
    pmax = fmaxf(pmax, __shfl_xor(pmax, 32));
    if (!__all(pmax - m_r <= 8.0f)) {
      float mnew = fmaxf(m_r, pmax);
      float sc_f = __builtin_amdgcn_exp2f(m_r - mnew);
      m_r = mnew;
      l_r *= sc_f;
#pragma unroll
      for (int d = 0; d < 4; ++d)
#pragma unroll
        for (int r = 0; r < 16; ++r) ot[d][r] *= sc_f;
    }
#pragma unroll
    for (int kvh = 0; kvh < 2; ++kvh)
#pragma unroll
      for (int r = 0; r < 16; ++r)
        st[kvh][r] = __builtin_amdgcn_exp2f(st[kvh][r] - m_r);
    float s8[8];
#pragma unroll
    for (int i = 0; i < 8; ++i)
      s8[i] = (st[0][i] + st[0][i + 8]) + (st[1][i] + st[1][i + 8]);
    float psum = ((s8[0] + s8[4]) + (s8[1] + s8[5])) +
                 ((s8[2] + s8[6]) + (s8[3] + s8[7]));
    psum += __shfl_xor(psum, 32);
    l_r += psum;

#pragma unroll
    for (int ks = 0; ks < 4; ++ks) {
      const int kvh = ks >> 1;
      const int r2a = (2 * ks) & 3;
      const int r2b = r2a + 1;
      unsigned ua0 = pack2(st[kvh][r2a * 4 + 0], st[kvh][r2a * 4 + 1]);
      unsigned ua1 = pack2(st[kvh][r2a * 4 + 2], st[kvh][r2a * 4 + 3]);
      unsigned ub0 = pack2(st[kvh][r2b * 4 + 0], st[kvh][r2b * 4 + 1]);
      unsigned ub1 = pack2(st[kvh][r2b * 4 + 2], st[kvh][r2b * 4 + 3]);
      union { unsigned u[4]; bf16x8 v8; } pw;
#if __has_builtin(__builtin_amdgcn_permlane32_swap)
      {
        auto r0 = __builtin_amdgcn_permlane32_swap(ua0, ub0, false, false);
        auto r1 = __builtin_amdgcn_permlane32_swap(ua1, ub1, false, false);
        pw.u[0] = r0[0];
        pw.u[1] = r1[0];
        pw.u[2] = r0[1];
        pw.u[3] = r1[1];
      }
#else
      {
        unsigned a0x = __shfl_xor(ua0, 32), a1x = __shfl_xor(ua1, 32);
        unsigned b0x = __shfl_xor(ub0, 32), b1x = __shfl_xor(ub1, 32);
        pw.u[0] = h ? b0x : ua0;
        pw.u[1] = h ? b1x : ua1;
        pw.u[2] = h ? ub0 : a0x;
        pw.u[3] = h ? ub1 : a1x;
      }
#endif
      __builtin_amdgcn_s_setprio(1);
#pragma unroll
      for (int db = 0; db < 4; ++db) {
        const unsigned base = (db & 1) ? Rv1 : Rv0;
        bf16x8 vf = *reinterpret_cast<const bf16x8*>(
            smem + cb + base + (unsigned)(ks * 4096 + db * 512));
        ot[db] = __builtin_amdgcn_mfma_f32_32x32x16_bf16(vf, pw.v8, ot[db], 0, 0, 0);
      }
      __builtin_amdgcn_s_setprio(0);
    }
  }

  __syncthreads();
  const float inv_l = 1.0f / l_r;
  const int qloc = wave * 32 + ql;
#pragma unroll
  for (int db = 0; db < 4; ++db)
#pragma unroll
    for (int r = 0; r < 16; ++r) {
      int d = db * 32 + (r & 3) + 8 * (r >> 2) + 4 * h;
      *reinterpret_cast<__bf16*>(smem + swz(qloc, qloc * 256u + d * 2u)) =
          (__bf16)(ot[db][r] * inv_l);
    }
  __syncthreads();
#pragma unroll
  for (int it = 0; it < 8; ++it) {
    int r = tid >> 1;
    int c = (tid & 1) * 64 + it * 8;
    bf16x8 val = *reinterpret_cast<const bf16x8*>(smem + swz(r, r * 256u + c * 2u));
    *reinterpret_cast<bf16x8*>(op + (size_t)(qbase + r) * D_DIM + c) = val;
  }
}

// ---------------------------------------------------------------------------
extern "C" void kernel_launch(void* const* d_in, const int* in_sizes, int n_in,
                              void* d_out, int out_size, void* d_ws, size_t ws_size,
                              hipStream_t stream) {
  const float* query = (const float*)d_in[0];
  const float* key_  = (const float*)d_in[1];
  const float* value = (const float*)d_in[2];
  const float* Wq = (const float*)d_in[3];
  const float* bq = (const float*)d_in[4];
  const float* Wk = (const float*)d_in[5];
  const float* bk = (const float*)d_in[6];
  const float* Wv = (const float*)d_in[7];
  const float* bv = (const float*)d_in[8];
  const float* Wo = (const float*)d_in[9];
  const float* bo = (const float*)d_in[10];

  const size_t nelem = (size_t)NTOK * D_DIM;
  const float qscale = 0.1275174490036f;  // log2(e)/sqrt(128)
  dim3 blk(256);

  if (ws_size >= 3 * nelem * sizeof(__bf16)) {
    // fused path: q,k,v all in d_ws (50.3 MB; round-12 proved >=84.4 MB).
    // d_out is written directly by the fused attn epilogue.
    __bf16* vws = (__bf16*)d_ws;
    __bf16* qws = vws + nelem;
    __bf16* kws = qws + nelem;

    qkv_proj_kernel<<<dim3(NTOK / 256, 3), blk, 0, stream>>>(
        query, key_, value, Wq, Wk, Wv, bq, bk, bv, qws, kws, vws, qscale);

    attn_fused_kernel<<<dim3(32, 16), blk, 0, stream>>>(
        qws, kws, vws, Wo, bo, (float*)d_out);
  } else {
    // fallback (r13 path): q/k scratch inside d_out, aws in d_ws
    __bf16* vws = (__bf16*)d_ws;
    __bf16* aws = vws + nelem;
    __bf16* qws = (__bf16*)d_out;
    __bf16* kws = qws + nelem;

    qkv_proj_kernel<<<dim3(NTOK / 256, 3), blk, 0, stream>>>(
        query, key_, value, Wq, Wk, Wv, bq, bk, bv, qws, kws, vws, qscale);

    attn_kernel<<<dim3(32, 16), blk, 0, stream>>>(qws, kws, vws, aws);

    o_proj_kernel<<<NTOK / 256, blk, 0, stream>>>(aws, Wo, bo, (float*)d_out);
  }
}